// Round 4
// baseline (2061.855 us; speedup 1.0000x reference)
//
#include <hip/hip_runtime.h>
#include <cstdint>
#include <cmath>

// ConvLSTM2D x2, B=8 T=10 H=W=64 Cin=32 F=64, split-bf16 MFMA implicit GEMM.
// Round 4: (1) x-conv and h-conv merged into one ky loop (same KS) -> half the
// barriers; (2) explicit B-fragment double-buffer prefetch (next tap-chunk's
// weights load during current 48 MFMAs); (3) grid 1024 x 128-thr blocks
// (2 waves = 2 gate-quarters) -> 4 independent barrier domains per CU;
// (4) direct global->LDS staging (no register relay).
// Verified-layout MFMA core and epilogue preserved from R2/R3.

#define NT  128     // step-kernel threads (2 waves)
#define NTU 256     // utility-kernel threads

typedef __attribute__((ext_vector_type(8))) short short8;
typedef __attribute__((ext_vector_type(4))) float f32x4;

__device__ __forceinline__ float hsig(float v) {
    return fminf(fmaxf(fmaf(v, 0.2f, 0.5f), 0.0f), 1.0f);
}

__device__ __forceinline__ short bf16rnd(float f) {
    union { float f; unsigned u; } a; a.f = f;
    return (short)((a.u + 0x7FFFu + ((a.u >> 16) & 1u)) >> 16);
}

__device__ __forceinline__ void split_bf16(float f, short& h, short& l) {
    h = bf16rnd(f);
    union { unsigned u; float f; } b; b.u = ((unsigned)(unsigned short)h) << 16;
    l = bf16rnd(f - b.f);
}

__device__ __forceinline__ float from_bf16(short s) {
    union { unsigned u; float f; } b; b.u = ((unsigned)(unsigned short)s) << 16;
    return b.f;
}

struct BF { uint4 bh[4]; uint4 bl[4]; };   // 4 gates x (hi,lo) fragments

// One ConvLSTM step, merged convs. Grid: 8 batch * 64 rows * 2 gate-halves
// = 1024 blocks, 128 threads. Wave w covers gate channels of fg = half*2+w.
// xp: x planes [px][2*CINX shorts]; h_prev planes [px][128 shorts].
template<int CINX, int KS, bool WRITE_SEQ>
__global__ __launch_bounds__(NT, 2)
void convlstm_step(
    const short* __restrict__ xp, long xp_bstride,     // shorts
    const short* __restrict__ h_prev,
    float* __restrict__ c_state,
    const short* __restrict__ Wpk,
    const short* __restrict__ Upk,
    const float* __restrict__ bias,
    short* __restrict__ h_next,
    short* __restrict__ seq, long seq_bstride)         // shorts
{
    constexpr int PAD  = KS / 2;
    constexpr int COLS = 64 + 2 * PAD;
    constexpr int CHX  = CINX / 32;
    constexpr int SEGS = CHX + 2;          // x chunks + 2 h chunks
    constexpr int PSTX = 2 * CINX + 8;     // shorts per px (x buf)
    constexpr int PSTH = 136;              // shorts per px (h buf)
    constexpr int VPPX = CINX / 4;         // uint4 per px (x)

    __shared__ __align__(16) short xs[COLS * PSTX];
    __shared__ __align__(16) short hs[COLS * PSTH];

    const int tid  = threadIdx.x;
    const int lane = tid & 63;
    const int wid  = tid >> 6;                 // 0..1
    const int q8   = ((lane >> 4) & 3) * 8;
    const int bi   = blockIdx.x;
    const int batch = bi >> 7;
    const int rem   = bi & 127;
    const int y     = rem >> 1;
    const int half  = rem & 1;
    const int fg    = half * 2 + wid;          // 0..3, 16 filters each

    const short* xim = xp + (size_t)batch * xp_bstride;
    const short* him = h_prev + (size_t)batch * 4096 * 128;

    // zero both LDS buffers (halo stays zero; interior overwritten per ky)
    for (int idx = tid; idx < (COLS * PSTX) / 8; idx += NT) {
        uint4 z; z.x = 0; z.y = 0; z.z = 0; z.w = 0;
        *(uint4*)(xs + idx * 8) = z;
    }
    for (int idx = tid; idx < (COLS * PSTH) / 8; idx += NT) {
        uint4 z; z.x = 0; z.y = 0; z.z = 0; z.w = 0;
        *(uint4*)(hs + idx * 8) = z;
    }

    f32x4 acc[4][4];
    #pragma unroll
    for (int g = 0; g < 4; ++g)
        #pragma unroll
        for (int mt = 0; mt < 4; ++mt)
            #pragma unroll
            for (int r = 0; r < 4; ++r) acc[g][mt][r] = 0.0f;

    // B-fragment loader: seg s<CHX -> Wpk chunk s; else Upk chunk s-CHX.
    auto loadB = [&](int ky, int kx, int s) -> BF {
        int tap = ky * KS + kx;
        const short* base;
        if (s < CHX)
            base = Wpk + ((size_t)((tap * CHX + s) * 16 + fg)) * 1024 + lane * 16;
        else
            base = Upk + ((size_t)((tap * 2 + (s - CHX)) * 16 + fg)) * 1024 + lane * 16;
        BF b;
        #pragma unroll
        for (int g = 0; g < 4; ++g) {
            b.bh[g] = *(const uint4*)(base + (size_t)g * 4096);
            b.bl[g] = *(const uint4*)(base + (size_t)g * 4096 + 8);
        }
        return b;
    };

    const int ky0   = (y < PAD) ? (PAD - y) : 0;
    const int kyend = (64 + PAD - y) < KS ? (64 + PAD - y) : KS;

    BF bcur = loadB(ky0, 0, 0);

    for (int ky = ky0; ky < kyend; ++ky) {
        int yin = y + ky - PAD;                     // always in [0,64)
        __syncthreads();                            // prior readers done
        const short* xrow = xim + (size_t)yin * 64 * 2 * CINX;
        for (int idx = tid; idx < 64 * VPPX; idx += NT) {
            int px = idx / VPPX;                    // pow2
            int v  = idx - px * VPPX;
            *(uint4*)(xs + (px + PAD) * PSTX + v * 8)
                = *(const uint4*)(xrow + px * 2 * CINX + v * 8);
        }
        const short* hrow = him + (size_t)yin * 64 * 128;
        for (int idx = tid; idx < 64 * 16; idx += NT) {
            int px = idx >> 4;
            int v  = idx & 15;
            *(uint4*)(hs + (px + PAD) * PSTH + v * 8)
                = *(const uint4*)(hrow + px * 128 + v * 8);
        }
        __syncthreads();

        #pragma unroll
        for (int kx = 0; kx < KS; ++kx) {
            #pragma unroll
            for (int s = 0; s < SEGS; ++s) {
                // next-iteration coords (clamped at the very end)
                int ns = s + 1, nkx = kx, nky = ky;
                if (ns == SEGS) { ns = 0; ++nkx; }
                if (nkx == KS)  { nkx = 0; ++nky; }
                if (nky >= kyend) { nky = ky; nkx = kx; ns = s; }
                BF bnxt = loadB(nky, nkx, ns);      // prefetch (global)

                short8 ah[4], al[4];
                #pragma unroll
                for (int mt = 0; mt < 4; ++mt) {
                    int col = mt * 16 + (lane & 15) + kx;
                    const short* p = (s < CHX)
                        ? (xs + col * PSTX + s * 32 + q8)
                        : (hs + col * PSTH + (s - CHX) * 32 + q8);
                    int lo = (s < CHX) ? CINX : 64;
                    ah[mt] = *(const short8*)p;
                    al[mt] = *(const short8*)(p + lo);
                }
                #pragma unroll
                for (int g = 0; g < 4; ++g) {
                    short8 bh = *(const short8*)&bcur.bh[g];
                    short8 bl = *(const short8*)&bcur.bl[g];
                    #pragma unroll
                    for (int mt = 0; mt < 4; ++mt) {
                        acc[g][mt] = __builtin_amdgcn_mfma_f32_16x16x32_bf16(
                            ah[mt], bh, acc[g][mt], 0, 0, 0);
                        acc[g][mt] = __builtin_amdgcn_mfma_f32_16x16x32_bf16(
                            al[mt], bh, acc[g][mt], 0, 0, 0);
                        acc[g][mt] = __builtin_amdgcn_mfma_f32_16x16x32_bf16(
                            ah[mt], bl, acc[g][mt], 0, 0, 0);
                    }
                }
                bcur = bnxt;
            }
        }
    }

    // ---- epilogue (layout identical to R3, verified) ----
    const int fl = fg * 16 + (lane & 15);
    const float b_i = bias[fl];
    const float b_f = bias[64 + fl];
    const float b_c = bias[128 + fl];
    const float b_o = bias[192 + fl];
    const int q = (lane >> 4) & 3;

    const long pixbase = (long)batch * 4096 + (long)y * 64;
    const long cb = pixbase * 64 + fl;
    const long sb = (long)batch * seq_bstride + ((long)y * 64) * 128 + fl;

    #pragma unroll
    for (int mt = 0; mt < 4; ++mt) {
        #pragma unroll
        for (int r = 0; r < 4; ++r) {
            int col = mt * 16 + q * 4 + r;
            long cidx = cb + (long)col * 64;
            float zi = acc[0][mt][r] + b_i;
            float zf = acc[1][mt][r] + b_f;
            float zc = acc[2][mt][r] + b_c;
            float zo = acc[3][mt][r] + b_o;
            float ig = hsig(zi);
            float fgt = hsig(zf);
            float og = hsig(zo);
            float cp = c_state[cidx];
            float cn = fgt * cp + ig * tanhf(zc);
            float hn = og * tanhf(cn);
            c_state[cidx] = cn;

            short hh, hl;
            split_bf16(hn, hh, hl);
            long hoff = (pixbase + col) * 128 + fl;
            h_next[hoff]      = hh;
            h_next[hoff + 64] = hl;
            if (WRITE_SEQ) {
                bool pos = hn > 0.0f;
                seq[sb + (long)col * 128]      = pos ? hh : (short)0;
                seq[sb + (long)col * 128 + 64] = pos ? hl : (short)0;
            }
        }
    }
}

// fp32 x [Npix][32] -> hi/lo planes [Npix]{32 hi,32 lo}. One thread = 4 ch.
__global__ void convert_planes32(const float4* __restrict__ src,
                                 unsigned* __restrict__ dst, int n4)
{
    int t = blockIdx.x * NTU + threadIdx.x;
    if (t >= n4) return;
    int pix = t >> 3;
    int c4  = t & 7;
    float4 v = src[t];
    short h0, l0, h1, l1, h2, l2, h3, l3;
    split_bf16(v.x, h0, l0);
    split_bf16(v.y, h1, l1);
    split_bf16(v.z, h2, l2);
    split_bf16(v.w, h3, l3);
    unsigned* p = dst + (size_t)pix * 32;
    p[c4 * 2]      = (unsigned)(unsigned short)h0 | ((unsigned)(unsigned short)h1 << 16);
    p[c4 * 2 + 1]  = (unsigned)(unsigned short)h2 | ((unsigned)(unsigned short)h3 << 16);
    p[16 + c4 * 2]     = (unsigned)(unsigned short)l0 | ((unsigned)(unsigned short)l1 << 16);
    p[16 + c4 * 2 + 1] = (unsigned)(unsigned short)l2 | ((unsigned)(unsigned short)l3 << 16);
}

// Repack fp32 weights [KS,KS,CIN,256] -> B-fragment hi/lo layout (verified R2).
__global__ void repack(const float* __restrict__ src, short* __restrict__ dst,
                       int KS, int CH)
{
    int total = KS * KS * CH * 16 * 64;
    int t = blockIdx.x * NTU + threadIdx.x;
    if (t >= total) return;
    int u = t >> 6, lane = t & 63;
    int tap = u / (CH * 16);
    int rem = u - tap * (CH * 16);
    int ch = rem >> 4;
    int gfg = rem & 15;
    int g = gfg >> 2, fgp = gfg & 3;
    int CIN = CH * 32;
    int n = lane & 15, qq = lane >> 4;
    short* d = dst + (size_t)u * 1024 + lane * 16;
    int gc = g * 64 + fgp * 16 + n;
    for (int j = 0; j < 8; ++j) {
        int c = ch * 32 + qq * 8 + j;
        float w = src[((size_t)tap * CIN + c) * 256 + gc];
        short h, l;
        split_bf16(w, h, l);
        d[j] = h;
        d[8 + j] = l;
    }
}

// out[b, t, pix, c] = relu(hi/lo planes h)
__global__ void relu_copy(const short* __restrict__ hp, float* __restrict__ out,
                          long out_bstride)
{
    long i = (long)blockIdx.x * NTU + threadIdx.x;   // 0 .. 2^21-1
    long pix = i >> 6;
    int c = (int)(i & 63);
    float f = from_bf16(hp[pix * 128 + c]) + from_bf16(hp[pix * 128 + 64 + c]);
    long b = pix >> 12;
    long within = (pix & 4095) * 64 + c;
    out[b * out_bstride + within] = fmaxf(f, 0.0f);
}

extern "C" void kernel_launch(void* const* d_in, const int* in_sizes, int n_in,
                              void* d_out, int out_size, void* d_ws, size_t ws_size,
                              hipStream_t stream) {
    const float* x   = (const float*)d_in[0];   // [8,10,64,64,32]
    const float* Wk1 = (const float*)d_in[1];   // [5,5,32,256]
    const float* Uk1 = (const float*)d_in[2];   // [5,5,64,256]
    const float* b1  = (const float*)d_in[3];   // [256]
    const float* Wk2 = (const float*)d_in[4];   // [3,3,64,256]
    const float* Uk2 = (const float*)d_in[5];   // [3,3,64,256]
    const float* b2  = (const float*)d_in[6];   // [256]
    float* out = (float*)d_out;                 // [8,10,64,64,64]

    const long S  = (long)8 * 64 * 64 * 64;     // 2,097,152 state elems
    const long oT = (long)64 * 64 * 64;         // out t-stride (floats)
    const long oB = 10 * oT;                    // out batch-stride (floats)

    short* h_a = (short*)d_ws;                  // h planes (2 shorts/elem)
    short* h_b = h_a + 2 * S;
    float* c_s = (float*)(h_b + 2 * S);
    short* Wp1 = (short*)(c_s + S);
    short* Up1 = Wp1 + 25 * 1 * 16 * 1024;
    short* Wp2 = Up1 + 25 * 2 * 16 * 1024;
    short* Up2 = Wp2 + 9 * 2 * 16 * 1024;
    short* x1p = Up2 + 9 * 2 * 16 * 1024;       // x planes: 8*10*4096*64 shorts
    (void)ws_size;

    {
        int n4 = 8 * 10 * 4096 * 8;
        convert_planes32<<<dim3((n4 + NTU - 1) / NTU), dim3(NTU), 0, stream>>>(
            (const float4*)x, (unsigned*)x1p, n4);
    }
    repack<<<dim3((25 * 1 * 16 * 64 + NTU - 1) / NTU), dim3(NTU), 0, stream>>>(Wk1, Wp1, 5, 1);
    repack<<<dim3((25 * 2 * 16 * 64 + NTU - 1) / NTU), dim3(NTU), 0, stream>>>(Uk1, Up1, 5, 2);
    repack<<<dim3((9 * 2 * 16 * 64 + NTU - 1) / NTU), dim3(NTU), 0, stream>>>(Wk2, Wp2, 3, 2);
    repack<<<dim3((9 * 2 * 16 * 64 + NTU - 1) / NTU), dim3(NTU), 0, stream>>>(Uk2, Up2, 3, 2);

    short* seqs = (short*)d_out;                // seq planes live in d_out slots

    // ---- layer 1 (x planes CIN=32, 5x5) ----
    hipMemsetAsync(h_a, 0, (size_t)S * 4, stream);
    hipMemsetAsync(c_s, 0, (size_t)S * 4, stream);
    short* hc = h_a;
    short* hn = h_b;
    const long x1T = (long)4096 * 64;
    const long x1B = 10 * x1T;
    for (int t = 0; t < 10; ++t) {
        convlstm_step<32, 5, true><<<dim3(1024), dim3(NT), 0, stream>>>(
            x1p + t * x1T, x1B, hc, c_s, Wp1, Up1, b1, hn,
            seqs + t * oT * 2, oB * 2);
        short* tmp = hc; hc = hn; hn = tmp;
    }

    // ---- layer 2 (x = seq planes CIN=64, 3x3) ----
    hipMemsetAsync(hc, 0, (size_t)S * 4, stream);
    hipMemsetAsync(c_s, 0, (size_t)S * 4, stream);
    for (int t = 0; t < 10; ++t) {
        convlstm_step<64, 3, false><<<dim3(1024), dim3(NT), 0, stream>>>(
            seqs + t * oT * 2, oB * 2, hc, c_s, Wp2, Up2, b2, hn,
            nullptr, 0);
        relu_copy<<<dim3(8192), dim3(NTU), 0, stream>>>(hn, out + t * oT, oB);
        short* tmp = hc; hc = hn; hn = tmp;
    }
}

// Round 5
// 1860.201 us; speedup vs baseline: 1.1084x; 1.1084x over previous
//
#include <hip/hip_runtime.h>
#include <cstdint>
#include <cmath>

// ConvLSTM2D x2, B=8 T=10 H=W=64 Cin=32 F=64, split-bf16 MFMA implicit GEMM.
// Round 5: R4's merged x+h ky loop and explicit B-fragment double-buffer,
// with R3's 256-thread blocks restored (4 waves = 4 gate groups, grid 512)
// so each (batch,row) is staged exactly once (R4's 128-thr split doubled
// staging traffic: FETCH 44->70 MB, net regression). Prefetch boundary
// clamp reduced to a single min().

#define NT  256     // step-kernel threads (4 waves)
#define NTU 256     // utility-kernel threads

typedef __attribute__((ext_vector_type(8))) short short8;
typedef __attribute__((ext_vector_type(4))) float f32x4;

__device__ __forceinline__ float hsig(float v) {
    return fminf(fmaxf(fmaf(v, 0.2f, 0.5f), 0.0f), 1.0f);
}

__device__ __forceinline__ short bf16rnd(float f) {
    union { float f; unsigned u; } a; a.f = f;
    return (short)((a.u + 0x7FFFu + ((a.u >> 16) & 1u)) >> 16);
}

__device__ __forceinline__ void split_bf16(float f, short& h, short& l) {
    h = bf16rnd(f);
    union { unsigned u; float f; } b; b.u = ((unsigned)(unsigned short)h) << 16;
    l = bf16rnd(f - b.f);
}

__device__ __forceinline__ float from_bf16(short s) {
    union { unsigned u; float f; } b; b.u = ((unsigned)(unsigned short)s) << 16;
    return b.f;
}

struct BF { uint4 bh[4]; uint4 bl[4]; };   // 4 gates x (hi,lo) fragments

// One ConvLSTM step, merged convs. Grid: 8 batch * 64 rows = 512 blocks,
// 256 threads; wave w handles gate filter-group fg = w.
// xp: x planes [px][2*CINX shorts]; h_prev planes [px][128 shorts].
template<int CINX, int KS, bool WRITE_SEQ>
__global__ __launch_bounds__(NT, 2)
void convlstm_step(
    const short* __restrict__ xp, long xp_bstride,     // shorts
    const short* __restrict__ h_prev,
    float* __restrict__ c_state,
    const short* __restrict__ Wpk,
    const short* __restrict__ Upk,
    const float* __restrict__ bias,
    short* __restrict__ h_next,
    short* __restrict__ seq, long seq_bstride)         // shorts
{
    constexpr int PAD  = KS / 2;
    constexpr int COLS = 64 + 2 * PAD;
    constexpr int CHX  = CINX / 32;
    constexpr int SEGS = CHX + 2;          // x chunks + 2 h chunks
    constexpr int PSTX = 2 * CINX + 8;     // shorts per px (x buf)
    constexpr int PSTH = 136;              // shorts per px (h buf)
    constexpr int VPPX = CINX / 4;         // uint4 per px (x)

    __shared__ __align__(16) short xs[COLS * PSTX];
    __shared__ __align__(16) short hs[COLS * PSTH];

    const int tid  = threadIdx.x;
    const int lane = tid & 63;
    const int fg   = tid >> 6;                 // 0..3 gate filter-group
    const int q8   = ((lane >> 4) & 3) * 8;
    const int batch = blockIdx.x >> 6;
    const int y     = blockIdx.x & 63;

    const short* xim = xp + (size_t)batch * xp_bstride;
    const short* him = h_prev + (size_t)batch * 4096 * 128;

    // zero both LDS buffers (halo stays zero; interior overwritten per ky)
    for (int idx = tid; idx < (COLS * PSTX) / 8; idx += NT) {
        uint4 z; z.x = 0; z.y = 0; z.z = 0; z.w = 0;
        *(uint4*)(xs + idx * 8) = z;
    }
    for (int idx = tid; idx < (COLS * PSTH) / 8; idx += NT) {
        uint4 z; z.x = 0; z.y = 0; z.z = 0; z.w = 0;
        *(uint4*)(hs + idx * 8) = z;
    }

    f32x4 acc[4][4];
    #pragma unroll
    for (int g = 0; g < 4; ++g)
        #pragma unroll
        for (int mt = 0; mt < 4; ++mt)
            #pragma unroll
            for (int r = 0; r < 4; ++r) acc[g][mt][r] = 0.0f;

    // B-fragment loader: seg s<CHX -> Wpk chunk s; else Upk chunk s-CHX.
    auto loadB = [&](int ky, int kx, int s) -> BF {
        int tap = ky * KS + kx;
        const short* base;
        if (s < CHX)
            base = Wpk + ((size_t)((tap * CHX + s) * 16 + fg)) * 1024 + lane * 16;
        else
            base = Upk + ((size_t)((tap * 2 + (s - CHX)) * 16 + fg)) * 1024 + lane * 16;
        BF b;
        #pragma unroll
        for (int g = 0; g < 4; ++g) {
            b.bh[g] = *(const uint4*)(base + (size_t)g * 4096);
            b.bl[g] = *(const uint4*)(base + (size_t)g * 4096 + 8);
        }
        return b;
    };

    const int ky0   = (y < PAD) ? (PAD - y) : 0;
    const int kyend = (64 + PAD - y) < KS ? (64 + PAD - y) : KS;

    BF bcur = loadB(ky0, 0, 0);

    for (int ky = ky0; ky < kyend; ++ky) {
        int yin = y + ky - PAD;                     // always in [0,64)
        __syncthreads();                            // prior readers done
        const short* xrow = xim + (size_t)yin * 64 * 2 * CINX;
        for (int idx = tid; idx < 64 * VPPX; idx += NT) {
            int px = idx / VPPX;                    // pow2
            int v  = idx - px * VPPX;
            *(uint4*)(xs + (px + PAD) * PSTX + v * 8)
                = *(const uint4*)(xrow + px * 2 * CINX + v * 8);
        }
        const short* hrow = him + (size_t)yin * 64 * 128;
        for (int idx = tid; idx < 64 * 16; idx += NT) {
            int px = idx >> 4;
            int v  = idx & 15;
            *(uint4*)(hs + (px + PAD) * PSTH + v * 8)
                = *(const uint4*)(hrow + px * 128 + v * 8);
        }
        __syncthreads();

        #pragma unroll
        for (int kx = 0; kx < KS; ++kx) {
            #pragma unroll
            for (int s = 0; s < SEGS; ++s) {
                // next (s,kx,ky) in iteration order; ky clamped (extra load
                // of a valid address on the final step, harmless)
                int ns = s + 1, nkx = kx, nky = ky;
                if (ns == SEGS) { ns = 0; ++nkx; }
                if (nkx == KS)  { nkx = 0; ++nky; }
                nky = (nky < kyend) ? nky : ky;
                BF bnxt = loadB(nky, nkx, ns);      // prefetch (global)

                short8 ah[4], al[4];
                #pragma unroll
                for (int mt = 0; mt < 4; ++mt) {
                    int col = mt * 16 + (lane & 15) + kx;
                    const short* p = (s < CHX)
                        ? (xs + col * PSTX + s * 32 + q8)
                        : (hs + col * PSTH + (s - CHX) * 32 + q8);
                    int lo = (s < CHX) ? CINX : 64;
                    ah[mt] = *(const short8*)p;
                    al[mt] = *(const short8*)(p + lo);
                }
                #pragma unroll
                for (int g = 0; g < 4; ++g) {
                    short8 bh = *(const short8*)&bcur.bh[g];
                    short8 bl = *(const short8*)&bcur.bl[g];
                    #pragma unroll
                    for (int mt = 0; mt < 4; ++mt) {
                        acc[g][mt] = __builtin_amdgcn_mfma_f32_16x16x32_bf16(
                            ah[mt], bh, acc[g][mt], 0, 0, 0);
                        acc[g][mt] = __builtin_amdgcn_mfma_f32_16x16x32_bf16(
                            al[mt], bh, acc[g][mt], 0, 0, 0);
                        acc[g][mt] = __builtin_amdgcn_mfma_f32_16x16x32_bf16(
                            ah[mt], bl, acc[g][mt], 0, 0, 0);
                    }
                }
                bcur = bnxt;
            }
        }
    }

    // ---- epilogue (layout identical to R2/R3, verified) ----
    const int fl = fg * 16 + (lane & 15);
    const float b_i = bias[fl];
    const float b_f = bias[64 + fl];
    const float b_c = bias[128 + fl];
    const float b_o = bias[192 + fl];
    const int q = (lane >> 4) & 3;

    const long pixbase = (long)batch * 4096 + (long)y * 64;
    const long cb = pixbase * 64 + fl;
    const long sb = (long)batch * seq_bstride + ((long)y * 64) * 128 + fl;

    #pragma unroll
    for (int mt = 0; mt < 4; ++mt) {
        #pragma unroll
        for (int r = 0; r < 4; ++r) {
            int col = mt * 16 + q * 4 + r;
            long cidx = cb + (long)col * 64;
            float zi = acc[0][mt][r] + b_i;
            float zf = acc[1][mt][r] + b_f;
            float zc = acc[2][mt][r] + b_c;
            float zo = acc[3][mt][r] + b_o;
            float ig = hsig(zi);
            float fgt = hsig(zf);
            float og = hsig(zo);
            float cp = c_state[cidx];
            float cn = fgt * cp + ig * tanhf(zc);
            float hn = og * tanhf(cn);
            c_state[cidx] = cn;

            short hh, hl;
            split_bf16(hn, hh, hl);
            long hoff = (pixbase + col) * 128 + fl;
            h_next[hoff]      = hh;
            h_next[hoff + 64] = hl;
            if (WRITE_SEQ) {
                bool pos = hn > 0.0f;
                seq[sb + (long)col * 128]      = pos ? hh : (short)0;
                seq[sb + (long)col * 128 + 64] = pos ? hl : (short)0;
            }
        }
    }
}

// fp32 x [Npix][32] -> hi/lo planes [Npix]{32 hi,32 lo}. One thread = 4 ch.
__global__ void convert_planes32(const float4* __restrict__ src,
                                 unsigned* __restrict__ dst, int n4)
{
    int t = blockIdx.x * NTU + threadIdx.x;
    if (t >= n4) return;
    int pix = t >> 3;
    int c4  = t & 7;
    float4 v = src[t];
    short h0, l0, h1, l1, h2, l2, h3, l3;
    split_bf16(v.x, h0, l0);
    split_bf16(v.y, h1, l1);
    split_bf16(v.z, h2, l2);
    split_bf16(v.w, h3, l3);
    unsigned* p = dst + (size_t)pix * 32;
    p[c4 * 2]      = (unsigned)(unsigned short)h0 | ((unsigned)(unsigned short)h1 << 16);
    p[c4 * 2 + 1]  = (unsigned)(unsigned short)h2 | ((unsigned)(unsigned short)h3 << 16);
    p[16 + c4 * 2]     = (unsigned)(unsigned short)l0 | ((unsigned)(unsigned short)l1 << 16);
    p[16 + c4 * 2 + 1] = (unsigned)(unsigned short)l2 | ((unsigned)(unsigned short)l3 << 16);
}

// Repack fp32 weights [KS,KS,CIN,256] -> B-fragment hi/lo layout (verified R2).
__global__ void repack(const float* __restrict__ src, short* __restrict__ dst,
                       int KS, int CH)
{
    int total = KS * KS * CH * 16 * 64;
    int t = blockIdx.x * NTU + threadIdx.x;
    if (t >= total) return;
    int u = t >> 6, lane = t & 63;
    int tap = u / (CH * 16);
    int rem = u - tap * (CH * 16);
    int ch = rem >> 4;
    int gfg = rem & 15;
    int g = gfg >> 2, fgp = gfg & 3;
    int CIN = CH * 32;
    int n = lane & 15, qq = lane >> 4;
    short* d = dst + (size_t)u * 1024 + lane * 16;
    int gc = g * 64 + fgp * 16 + n;
    for (int j = 0; j < 8; ++j) {
        int c = ch * 32 + qq * 8 + j;
        float w = src[((size_t)tap * CIN + c) * 256 + gc];
        short h, l;
        split_bf16(w, h, l);
        d[j] = h;
        d[8 + j] = l;
    }
}

// out[b, t, pix, c] = relu(hi/lo planes h)
__global__ void relu_copy(const short* __restrict__ hp, float* __restrict__ out,
                          long out_bstride)
{
    long i = (long)blockIdx.x * NTU + threadIdx.x;   // 0 .. 2^21-1
    long pix = i >> 6;
    int c = (int)(i & 63);
    float f = from_bf16(hp[pix * 128 + c]) + from_bf16(hp[pix * 128 + 64 + c]);
    long b = pix >> 12;
    long within = (pix & 4095) * 64 + c;
    out[b * out_bstride + within] = fmaxf(f, 0.0f);
}

extern "C" void kernel_launch(void* const* d_in, const int* in_sizes, int n_in,
                              void* d_out, int out_size, void* d_ws, size_t ws_size,
                              hipStream_t stream) {
    const float* x   = (const float*)d_in[0];   // [8,10,64,64,32]
    const float* Wk1 = (const float*)d_in[1];   // [5,5,32,256]
    const float* Uk1 = (const float*)d_in[2];   // [5,5,64,256]
    const float* b1  = (const float*)d_in[3];   // [256]
    const float* Wk2 = (const float*)d_in[4];   // [3,3,64,256]
    const float* Uk2 = (const float*)d_in[5];   // [3,3,64,256]
    const float* b2  = (const float*)d_in[6];   // [256]
    float* out = (float*)d_out;                 // [8,10,64,64,64]

    const long S  = (long)8 * 64 * 64 * 64;     // 2,097,152 state elems
    const long oT = (long)64 * 64 * 64;         // out t-stride (floats)
    const long oB = 10 * oT;                    // out batch-stride (floats)

    short* h_a = (short*)d_ws;                  // h planes (2 shorts/elem)
    short* h_b = h_a + 2 * S;
    float* c_s = (float*)(h_b + 2 * S);
    short* Wp1 = (short*)(c_s + S);
    short* Up1 = Wp1 + 25 * 1 * 16 * 1024;
    short* Wp2 = Up1 + 25 * 2 * 16 * 1024;
    short* Up2 = Wp2 + 9 * 2 * 16 * 1024;
    short* x1p = Up2 + 9 * 2 * 16 * 1024;       // x planes: 8*10*4096*64 shorts
    (void)ws_size;

    {
        int n4 = 8 * 10 * 4096 * 8;
        convert_planes32<<<dim3((n4 + NTU - 1) / NTU), dim3(NTU), 0, stream>>>(
            (const float4*)x, (unsigned*)x1p, n4);
    }
    repack<<<dim3((25 * 1 * 16 * 64 + NTU - 1) / NTU), dim3(NTU), 0, stream>>>(Wk1, Wp1, 5, 1);
    repack<<<dim3((25 * 2 * 16 * 64 + NTU - 1) / NTU), dim3(NTU), 0, stream>>>(Uk1, Up1, 5, 2);
    repack<<<dim3((9 * 2 * 16 * 64 + NTU - 1) / NTU), dim3(NTU), 0, stream>>>(Wk2, Wp2, 3, 2);
    repack<<<dim3((9 * 2 * 16 * 64 + NTU - 1) / NTU), dim3(NTU), 0, stream>>>(Uk2, Up2, 3, 2);

    short* seqs = (short*)d_out;                // seq planes live in d_out slots

    // ---- layer 1 (x planes CIN=32, 5x5) ----
    hipMemsetAsync(h_a, 0, (size_t)S * 4, stream);
    hipMemsetAsync(c_s, 0, (size_t)S * 4, stream);
    short* hc = h_a;
    short* hn = h_b;
    const long x1T = (long)4096 * 64;
    const long x1B = 10 * x1T;
    for (int t = 0; t < 10; ++t) {
        convlstm_step<32, 5, true><<<dim3(512), dim3(NT), 0, stream>>>(
            x1p + t * x1T, x1B, hc, c_s, Wp1, Up1, b1, hn,
            seqs + t * oT * 2, oB * 2);
        short* tmp = hc; hc = hn; hn = tmp;
    }

    // ---- layer 2 (x = seq planes CIN=64, 3x3) ----
    hipMemsetAsync(hc, 0, (size_t)S * 4, stream);
    hipMemsetAsync(c_s, 0, (size_t)S * 4, stream);
    for (int t = 0; t < 10; ++t) {
        convlstm_step<64, 3, false><<<dim3(512), dim3(NT), 0, stream>>>(
            seqs + t * oT * 2, oB * 2, hc, c_s, Wp2, Up2, b2, hn,
            nullptr, 0);
        relu_copy<<<dim3(8192), dim3(NTU), 0, stream>>>(hn, out + t * oT, oB);
        short* tmp = hc; hc = hn; hn = tmp;
    }
}